// Round 9
// baseline (270.375 us; speedup 1.0000x reference)
//
#include <hip/hip_runtime.h>

#define B_ 4
#define T_ 2048
#define C_ 1024
#define H_ 16
#define D_ 64

typedef __attribute__((ext_vector_type(8))) short short8;
typedef __attribute__((ext_vector_type(4))) float f32x4;

// float -> bf16 round-to-nearest-even (fallback)
__device__ inline unsigned short f2bf(float f) {
    union { float f; unsigned u; } v; v.f = f;
    unsigned r = v.u + 0x7fffu + ((v.u >> 16) & 1u);
    return (unsigned short)(r >> 16);
}

// pack two fp32 -> packed bf16x2 (v_cvt_pk_bf16_f32 on gfx950)
__device__ inline unsigned int pk_bf16(float a, float b) {
#if __has_builtin(__builtin_amdgcn_cvt_pk_bf16_f32)
    typedef __attribute__((ext_vector_type(2))) __bf16 bf16x2;
    bf16x2 v = __builtin_amdgcn_cvt_pk_bf16_f32(a, b);
    return __builtin_bit_cast(unsigned int, v);
#else
    return (unsigned)f2bf(a) | ((unsigned)f2bf(b) << 16);
#endif
}

// async 16B global -> LDS (wave-uniform LDS base + lane*16)
__device__ inline void async_ld16(const void* g, void* lds) {
    __builtin_amdgcn_global_load_lds(
        (const __attribute__((address_space(1))) unsigned int*)g,
        (__attribute__((address_space(3))) unsigned int*)lds, 16, 0, 0);
}

#define MFMA_BF16 __builtin_amdgcn_mfma_f32_16x16x32_bf16

// ---------------------------------------------------------------------------
// Merged prep: bid<8192 -> x fp32->bf16 convert; else 32x32 transpose-convert
// of w_qkv (128 col-tiles) / w_proj (32 col-tiles) into [n][k] bf16.
// (unchanged; passing)
// ---------------------------------------------------------------------------
__global__ __launch_bounds__(256) void prep_all(
    const float* __restrict__ x, const float* __restrict__ w_qkv,
    const float* __restrict__ w_proj,
    unsigned short* __restrict__ xb, unsigned short* __restrict__ wqkvT,
    unsigned short* __restrict__ wprojT)
{
    const int bid = blockIdx.x;
    if (bid < 8192) {
        int i = (bid * 256 + threadIdx.x) * 4;
        float4 v = *(const float4*)(x + i);
        uint2 o;
        o.x = pk_bf16(v.x, v.y);
        o.y = pk_bf16(v.z, v.w);
        *(uint2*)(xb + i) = o;
        return;
    }
    __shared__ float tile[32][33];
    const int tt = bid - 8192;          // 0..4095
    int bx = tt & 127;                  // col tile
    const int by = tt >> 7;             // row tile (0..31)
    const float* src; unsigned short* dst; int Cc;
    if (bx < 96) { src = w_qkv;  dst = wqkvT;  Cc = 3072; }
    else         { src = w_proj; dst = wprojT; Cc = 1024; bx -= 96; }
    const int tx = threadIdx.x & 31, ty = threadIdx.x >> 5;
    #pragma unroll
    for (int r = 0; r < 32; r += 8)
        tile[ty + r][tx] = src[(size_t)(by*32 + ty + r) * Cc + bx*32 + tx];
    __syncthreads();
    #pragma unroll
    for (int r = 0; r < 32; r += 8)
        dst[(size_t)(bx*32 + ty + r) * 1024 + by*32 + tx] = f2bf(tile[tx][ty + r]);
}

// ---------------------------------------------------------------------------
// QKV GEMM v6: round-6 skeleton (128x128 tile, 256 threads, double-buffered
// LDS, prefetch-before-compute, __syncthreads-only sync — the proven-best
// structure) with the buffer shrunk BK=64 -> BK=32: 2 x (8KB A + 8KB B) =
// 32KB LDS -> 4 blocks/CU (VGPR=120 allows 16 waves).  R6 ran 2 blocks/CU;
// its counters (MfmaUtil 30%, VALU 21%, HBM 17%, conflicts 0 — nothing
// saturated) say latency-bound with too little cross-block wave overlap
// (m114 mechanism).  Doubling resident blocks doubles the waves that can
// compute while another block sits in the __syncthreads vmcnt-drain.
// BK=32 conflict-free layout from R7's passing kernel: 64B rows, source
// chunk XOR (row>>1)&3, read chunk lq ^ ((l15>>1)&3) -> 2 lanes/bank (free).
// Epilogues byte-identical to R6.  Grid: 1536 = 8 xcd x 8 m_l x 24 n.
// ---------------------------------------------------------------------------
__global__ __launch_bounds__(256) void gemm_qkv(
    const unsigned short* __restrict__ A,   // [8192][1024] bf16
    const unsigned short* __restrict__ BT,  // [3072][1024] bf16
    const float* __restrict__ bias,         // [3072] fp32
    unsigned short* __restrict__ qb, unsigned short* __restrict__ kb,
    unsigned short* __restrict__ vtb)
{
    __shared__ unsigned short As[2][128 * 32];   // 2 x 8KB, 64B rows
    __shared__ unsigned short Bs[2][128 * 32];   // 2 x 8KB
    const int tid = threadIdx.x;
    const int wave = tid >> 6, lane = tid & 63;
    const int wm = wave >> 1, wn = wave & 1;
    const int l15 = lane & 15, lq = lane >> 4;
    const int bid = blockIdx.x;
    const int xcd = bid & 7, idx = bid >> 3;         // idx: 0..191
    const int m0 = (xcd * 8 + (idx & 7)) * 128;      // 64 m-tiles
    const int n0 = (idx >> 3) * 128;                 // 24 n-tiles
    const int sel = n0 >> 10;                        // 0=q 1=k 2=v
    // stage: row = R0 + (lane>>2), dest chunk lane&3, src chunk XOR (row>>1)&3
    const int schx = ((lane & 3) ^ ((lane >> 3) & 3)) * 8;   // elems
    // read: chunk byte offset lq ^ ((row>>1)&3), row == l15 (mod 16)
    const int rdch = ((lq ^ ((l15 >> 1) & 3)) << 4);         // bytes

    f32x4 acc[4][4] = {};

#define STAGE(buf, K0) do { _Pragma("unroll") \
    for (int c = 0; c < 2; ++c) { \
        const int R0 = (wave*2 + c) * 16; \
        async_ld16(A  + (size_t)(m0 + R0 + (lane >> 2))*1024 + (K0) + schx, \
                   (char*)&As[buf][0] + R0*64); \
        async_ld16(BT + (size_t)(n0 + R0 + (lane >> 2))*1024 + (K0) + schx, \
                   (char*)&Bs[buf][0] + R0*64); \
    } } while (0)

    STAGE(0, 0);
    __syncthreads();                       // buf0 ready

    for (int t = 0; t < 32; ++t) {
        const int cur = t & 1;
        if (t < 31) STAGE(cur ^ 1, (t + 1) << 5);   // prefetch under compute
        const char* Ac = (const char*)&As[cur][0];
        const char* Bc = (const char*)&Bs[cur][0];
        short8 af[4], bf[4];
        #pragma unroll
        for (int i = 0; i < 4; ++i) {
            af[i] = *(const short8*)(Ac + (wm*64 + i*16 + l15)*64 + rdch);
            bf[i] = *(const short8*)(Bc + (wn*64 + i*16 + l15)*64 + rdch);
        }
        if (sel < 2) {
            #pragma unroll
            for (int mi = 0; mi < 4; ++mi)
                #pragma unroll
                for (int ni = 0; ni < 4; ++ni)
                    acc[mi][ni] = MFMA_BF16(bf[ni], af[mi], acc[mi][ni], 0, 0, 0);
        } else {
            #pragma unroll
            for (int mi = 0; mi < 4; ++mi)
                #pragma unroll
                for (int ni = 0; ni < 4; ++ni)
                    acc[mi][ni] = MFMA_BF16(af[mi], bf[ni], acc[mi][ni], 0, 0, 0);
        }
        __syncthreads();   // publishes buf[t+1] + retires reads of buf[t]
    }
#undef STAGE

    if (sel < 2) {
        // lane l15 -> t; reg r -> d. 4 consecutive d per lane -> 8B store.
        const float qs = (sel == 0) ? 0.180336880f : 1.0f;  // 0.125*log2(e) | 1
        unsigned short* dst = (sel == 0) ? qb : kb;
        #pragma unroll
        for (int mi = 0; mi < 4; ++mi) {
            const int t = m0 + wm*64 + mi*16 + l15;
            const int bb = t >> 11, tt = t & 2047;
            #pragma unroll
            for (int ni = 0; ni < 4; ++ni) {
                const int nb = n0 + wn*64 + ni*16 + lq*4;
                const int hh = (nb >> 6) & 15, d0 = nb & 63;
                float4 bv = *(const float4*)(bias + nb);
                float v0 = (acc[mi][ni][0] + bv.x) * qs;
                float v1 = (acc[mi][ni][1] + bv.y) * qs;
                float v2 = (acc[mi][ni][2] + bv.z) * qs;
                float v3 = (acc[mi][ni][3] + bv.w) * qs;
                uint2 pk; pk.x = pk_bf16(v0, v1); pk.y = pk_bf16(v2, v3);
                *(uint2*)(dst + ((size_t)(bb*16 + hh)*2048 + tt)*64 + d0) = pk;
            }
        }
    } else {
        // lane l15 -> d; reg r -> t. 4 consecutive t per lane -> 8B store.
        // column permuted within each 64-tile: t' = c<<5 | lq2<<3 | h<<2 | r
        #pragma unroll
        for (int mi = 0; mi < 4; ++mi) {
            const int t0 = m0 + wm*64 + mi*16 + lq*4;
            const int bb = t0 >> 11, tt = t0 & 2047;
            const int tl = tt & 63;
            const int tp = (tt & ~63) | (tl & 32) | ((tl & 12) << 1) | ((tl & 16) >> 2);
            #pragma unroll
            for (int ni = 0; ni < 4; ++ni) {
                const int n = n0 + wn*64 + ni*16 + l15;
                const int hh = (n >> 6) & 15, d = n & 63;
                const float bs = bias[n];
                uint2 pk;
                pk.x = pk_bf16(acc[mi][ni][0] + bs, acc[mi][ni][1] + bs);
                pk.y = pk_bf16(acc[mi][ni][2] + bs, acc[mi][ni][3] + bs);
                *(uint2*)(vtb + ((size_t)(bb*16 + hh)*64 + d)*2048 + tp) = pk;
            }
        }
    }
}

// ---------------------------------------------------------------------------
// Output projection GEMM v6: same BK=32 dbuf structure (32KB -> 4 blocks/CU),
// swapped operands -> float4 coalesced stores.  Grid: 512 = 8 xcd x 8 m_l
// x 8 n.
// ---------------------------------------------------------------------------
__global__ __launch_bounds__(256) void gemm_proj(
    const unsigned short* __restrict__ A,   // [8192][1024] bf16
    const unsigned short* __restrict__ BT,  // [1024][1024] bf16
    const float* __restrict__ bias,         // [1024]
    float* __restrict__ out)
{
    __shared__ unsigned short As[2][128 * 32];
    __shared__ unsigned short Bs[2][128 * 32];
    const int tid = threadIdx.x;
    const int wave = tid >> 6, lane = tid & 63;
    const int wm = wave >> 1, wn = wave & 1;
    const int l15 = lane & 15, lq = lane >> 4;
    const int bid = blockIdx.x;
    const int xcd = bid & 7, idx = bid >> 3;         // idx: 0..63
    const int m0 = (xcd * 8 + (idx & 7)) * 128;      // 64 m-tiles
    const int n0 = (idx >> 3) * 128;                 // 8 n-tiles
    const int schx = ((lane & 3) ^ ((lane >> 3) & 3)) * 8;
    const int rdch = ((lq ^ ((l15 >> 1) & 3)) << 4);

    f32x4 acc[4][4] = {};

#define PSTAGE(buf, K0) do { _Pragma("unroll") \
    for (int c = 0; c < 2; ++c) { \
        const int R0 = (wave*2 + c) * 16; \
        async_ld16(A  + (size_t)(m0 + R0 + (lane >> 2))*1024 + (K0) + schx, \
                   (char*)&As[buf][0] + R0*64); \
        async_ld16(BT + (size_t)(n0 + R0 + (lane >> 2))*1024 + (K0) + schx, \
                   (char*)&Bs[buf][0] + R0*64); \
    } } while (0)

    PSTAGE(0, 0);
    __syncthreads();

    for (int t = 0; t < 32; ++t) {
        const int cur = t & 1;
        if (t < 31) PSTAGE(cur ^ 1, (t + 1) << 5);
        const char* Ac = (const char*)&As[cur][0];
        const char* Bc = (const char*)&Bs[cur][0];
        short8 af[4], bf[4];
        #pragma unroll
        for (int i = 0; i < 4; ++i) {
            af[i] = *(const short8*)(Ac + (wm*64 + i*16 + l15)*64 + rdch);
            bf[i] = *(const short8*)(Bc + (wn*64 + i*16 + l15)*64 + rdch);
        }
        #pragma unroll
        for (int mi = 0; mi < 4; ++mi)
            #pragma unroll
            for (int ni = 0; ni < 4; ++ni)
                acc[mi][ni] = MFMA_BF16(bf[ni], af[mi], acc[mi][ni], 0, 0, 0);
        __syncthreads();
    }
#undef PSTAGE

    #pragma unroll
    for (int mi = 0; mi < 4; ++mi) {
        const int m = m0 + wm*64 + mi*16 + l15;
        #pragma unroll
        for (int ni = 0; ni < 4; ++ni) {
            const int nb = n0 + wn*64 + ni*16 + lq*4;
            float4 bv = *(const float4*)(bias + nb);
            float4 o;
            o.x = acc[mi][ni][0] + bv.x;
            o.y = acc[mi][ni][1] + bv.y;
            o.z = acc[mi][ni][2] + bv.z;
            o.w = acc[mi][ni][3] + bv.w;
            *(float4*)(out + (size_t)m * 1024 + nb) = o;
        }
    }
}

// ---------------------------------------------------------------------------
// MFMA flash attention v5 (byte-identical to the passing build): no-max
// exp2 softmax, 4 waves split k-tiles, private K/V LDS regions, counted-
// vmcnt pipeline, no barriers in main loop, P stays in registers (swapped
// QK^T + pre-permuted V layout).  Cross-wave o/l combine at end.
// ---------------------------------------------------------------------------
__global__ __launch_bounds__(256, 2) void attn_mfma(
    const unsigned short* __restrict__ qb,   // [B,H,T,D]
    const unsigned short* __restrict__ kb,   // [B,H,T,D]
    const unsigned short* __restrict__ vtb,  // [B,H,D,T'] (64-tile permuted)
    unsigned short* __restrict__ ab)         // [B*T][C]
{
    extern __shared__ unsigned char smem[];  // 4 x 16KB wave regions = 64KB
    const int tid  = threadIdx.x;
    const int wave = tid >> 6, lane = tid & 63;
    const int l15  = lane & 15, lq = lane >> 4;
    const int linear = blockIdx.x;
    const int xc  = linear & 7;            // XCD class
    const int idx = linear >> 3;
    const int bh  = xc * 8 + (idx & 7);    // 8 bh per XCD class
    const int qblk = 31 - (idx >> 3);      // heavy q-tiles dispatch first
    const int q0 = qblk * 64;
    const int b = bh >> 4, h = bh & 15;
    const size_t base = (size_t)bh * 2048 * 64;

    unsigned short* Kw = (unsigned short*)(smem + wave * 16384);  // 8KB
    unsigned short* Vw = Kw + 4096;                               // 8KB

    const int row8 = lane >> 3;                 // 0..7
    const int chx8 = ((lane & 7) ^ row8) * 8;   // XOR-swizzled source chunk

#define STAGE_K(J0) do { _Pragma("unroll") for (int op = 0; op < 8; ++op) \
    async_ld16(kb + base + (size_t)((J0) + op*8 + row8)*64 + chx8, \
               (char*)Kw + op*1024); } while (0)
#define STAGE_V(J0) do { _Pragma("unroll") for (int op = 0; op < 8; ++op) \
    async_ld16(vtb + base + (size_t)(op*8 + row8)*2048 + (J0) + chx8, \
               (char*)Vw + op*1024); } while (0)

    // Q fragments (B-operand), hoisted to registers: qf[ks][nq]
    short8 qf[2][4];
    #pragma unroll
    for (int ks = 0; ks < 2; ++ks)
        #pragma unroll
        for (int nq = 0; nq < 4; ++nq)
            qf[ks][nq] = *(const short8*)(qb + base
                + (size_t)(q0 + nq*16 + l15)*64 + ks*32 + lq*8);

    f32x4 o[4][4] = {};          // [nq][nd]: q=nq*16+lq*4+r, d=nd*16+l15
    float lacc[4] = {0.f, 0.f, 0.f, 0.f};

    const int jfirst = wave * 64;
    const int nt = (qblk >= wave) ? ((qblk - wave) >> 2) + 1 : 0;

    if (nt > 0) { STAGE_K(jfirst); STAGE_V(jfirst); }

    for (int i = 0; i < nt; ++i) {
        const int j0 = jfirst + i * 256;
        const bool more = (i + 1 < nt);

        // K(t) ready (V(t)'s 8 loads remain outstanding)
        asm volatile("s_waitcnt vmcnt(8)" ::: "memory");

        // ---- QK^T (swapped): s[ni][nq], k=ni*16+lq*4+r, q=nq*16+l15 ----
        short8 kf0[4], kf1[4];
        #pragma unroll
        for (int ni = 0; ni < 4; ++ni) {
            const unsigned short* kr = Kw + (ni*16 + l15) * 64;
            kf0[ni] = *(const short8*)(kr + (((0*4 + lq) ^ (l15 & 7)) << 3));
            kf1[ni] = *(const short8*)(kr + (((1*4 + lq) ^ (l15 & 7)) << 3));
        }
        f32x4 s[4][4] = {};
        #pragma unroll
        for (int ni = 0; ni < 4; ++ni)
            #pragma unroll
            for (int nq = 0; nq < 4; ++nq) {
                s[ni][nq] = MFMA_BF16(kf0[ni], qf[0][nq], s[ni][nq], 0, 0, 0);
                s[ni][nq] = MFMA_BF16(kf1[ni], qf[1][nq], s[ni][nq], 0, 0, 0);
            }
        // K reads retired -> safe to overwrite K buffer with next tile
        asm volatile("s_waitcnt lgkmcnt(0)" ::: "memory");
        if (more) STAGE_K(j0 + 256);

        // ---- causal mask (diagonal tile only) ----
        if (j0 == q0) {
            #pragma unroll
            for (int ni = 0; ni < 4; ++ni)
                #pragma unroll
                for (int nq = 0; nq < 4; ++nq)
                    #pragma unroll
                    for (int r = 0; r < 4; ++r)
                        if (ni*16 + lq*4 + r > nq*16 + l15)
                            s[ni][nq][r] = -1e30f;
        }

        // ---- p = exp2(s); pack PV A-fragments in-lane; accumulate l ----
        short8 pf[2][4];
        #pragma unroll
        for (int c = 0; c < 2; ++c)
            #pragma unroll
            for (int nq = 0; nq < 4; ++nq) {
                float p0 = __builtin_amdgcn_exp2f(s[2*c  ][nq][0]);
                float p1 = __builtin_amdgcn_exp2f(s[2*c  ][nq][1]);
                float p2 = __builtin_amdgcn_exp2f(s[2*c  ][nq][2]);
                float p3 = __builtin_amdgcn_exp2f(s[2*c  ][nq][3]);
                float p4 = __builtin_amdgcn_exp2f(s[2*c+1][nq][0]);
                float p5 = __builtin_amdgcn_exp2f(s[2*c+1][nq][1]);
                float p6 = __builtin_amdgcn_exp2f(s[2*c+1][nq][2]);
                float p7 = __builtin_amdgcn_exp2f(s[2*c+1][nq][3]);
                lacc[nq] += ((p0 + p1) + (p2 + p3)) + ((p4 + p5) + (p6 + p7));
                uint4 pu;
                pu.x = pk_bf16(p0, p1); pu.y = pk_bf16(p2, p3);
                pu.z = pk_bf16(p4, p5); pu.w = pk_bf16(p6, p7);
                pf[c][nq] = __builtin_bit_cast(short8, pu);
            }

        // V(t) ready (K(t+1) outstanding if issued)
        if (more) asm volatile("s_waitcnt vmcnt(8)" ::: "memory");
        else      asm volatile("s_waitcnt vmcnt(0)" ::: "memory");

        // ---- PV: o[nq][nd] += pf[c][nq] x vf[c][nd] ----
        #pragma unroll
        for (int c = 0; c < 2; ++c) {
            short8 vf[4];
            #pragma unroll
            for (int nd = 0; nd < 4; ++nd)
                vf[nd] = *(const short8*)(Vw + (nd*16 + l15) * 64
                    + (((c*4 + lq) ^ (l15 & 7)) << 3));
            #pragma unroll
            for (int nq = 0; nq < 4; ++nq)
                #pragma unroll
                for (int nd = 0; nd < 4; ++nd)
                    o[nq][nd] = MFMA_BF16(pf[c][nq], vf[nd], o[nq][nd], 0, 0, 0);
        }
        // V reads retired -> safe to overwrite V buffer
        asm volatile("s_waitcnt lgkmcnt(0)" ::: "memory");
        if (more) STAGE_V(j0 + 256);
    }
#undef STAGE_K
#undef STAGE_V

    // ---- cross-wave combine ----
    // 1) per-wave l partials (reduce over lq groups), store 64 f32 per region
    #pragma unroll
    for (int nq = 0; nq < 4; ++nq) {
        float t = lacc[nq];
        t += __shfl_xor(t, 16);
        t += __shfl_xor(t, 32);
        if (lq == 0) ((float*)Kw)[nq*16 + l15] = t;
    }
    __syncthreads();
    // 2) each thread computes linv for its 16 q rows (qg = wave)
    const int qg = wave, d = lane;
    f32x4 linv4[4];
    #pragma unroll
    for (int j = 0; j < 4; ++j) {
        f32x4 lsum = {};
        #pragma unroll
        for (int w2 = 0; w2 < 4; ++w2)
            lsum += *(const f32x4*)((const float*)(smem + w2*16384) + qg*16 + j*4);
        #pragma unroll
        for (int r = 0; r < 4; ++r)
            linv4[j][r] = __builtin_amdgcn_rcpf(lsum[r]);
    }
    __syncthreads();
    // 3) write O partials (rotated cols: col = (q + 4*(d&15)) & 63)
    #pragma unroll
    for (int nq = 0; nq < 4; ++nq)
        #pragma unroll
        for (int nd = 0; nd < 4; ++nd) {
            const int row = nd*16 + l15;
            const int col = (nq*16 + lq*4 + 4*l15) & 63;
            *(f32x4*)((float*)Kw + row*64 + col) = o[nq][nd];
        }
    __syncthreads();
    // 4) sum 4 partials, normalize, store bf16 (coalesced 128B per wave-store)
    #pragma unroll
    for (int j = 0; j < 4; ++j) {
        const int colb = (qg*16 + j*4 + 4*(d & 15)) & 63;
        f32x4 acc = {};
        #pragma unroll
        for (int w2 = 0; w2 < 4; ++w2)
            acc += *(const f32x4*)((const float*)(smem + w2*16384) + d*64 + colb);
        #pragma unroll
        for (int r = 0; r < 4; ++r) {
            const int q = qg*16 + j*4 + r;
            ab[(size_t)(b*2048 + q0 + q)*1024 + h*64 + d] = f2bf(acc[r] * linv4[j][r]);
        }
    }
}

extern "C" void kernel_launch(void* const* d_in, const int* in_sizes, int n_in,
                              void* d_out, int out_size, void* d_ws, size_t ws_size,
                              hipStream_t stream) {
    const float* x      = (const float*)d_in[0];   // [B,T,C]
    const float* w_qkv  = (const float*)d_in[1];   // [C,3C]
    const float* b_qkv  = (const float*)d_in[2];   // [3C]
    const float* w_proj = (const float*)d_in[3];   // [C,C]
    const float* b_proj = (const float*)d_in[4];   // [C]
    float* out = (float*)d_out;                    // [B,T,C] fp32

    unsigned short* xb     = (unsigned short*)d_ws;          // 8192*1024
    unsigned short* wqkvT  = xb + 8388608;                   // 3072*1024
    unsigned short* wprojT = wqkvT + 3145728;                // 1024*1024
    unsigned short* qbuf   = wprojT + 1048576;               // [B,H,T,D]
    unsigned short* kbuf   = qbuf + 8388608;                 // [B,H,T,D]
    unsigned short* vtbuf  = kbuf + 8388608;                 // [B,H,D,T']
    unsigned short* abuf   = vtbuf + 8388608;                // [B*T][C]
    // total: 46,137,344 bf16 elems = 92 MiB

    prep_all<<<12288, 256, 0, stream>>>(x, w_qkv, w_proj, xb, wqkvT, wprojT);
    gemm_qkv<<<1536, 256, 0, stream>>>(xb, wqkvT, b_qkv, qbuf, kbuf, vtbuf);
    attn_mfma<<<2048, 256, 65536, stream>>>(qbuf, kbuf, vtbuf, abuf);
    gemm_proj<<<512, 256, 0, stream>>>(abuf, wprojT, b_proj, out);
}

// Round 11
// 260.590 us; speedup vs baseline: 1.0375x; 1.0375x over previous
//
#include <hip/hip_runtime.h>

#define B_ 4
#define T_ 2048
#define C_ 1024
#define H_ 16
#define D_ 64

typedef __attribute__((ext_vector_type(8))) short short8;
typedef __attribute__((ext_vector_type(4))) float f32x4;

// float -> bf16 round-to-nearest-even (fallback)
__device__ inline unsigned short f2bf(float f) {
    union { float f; unsigned u; } v; v.f = f;
    unsigned r = v.u + 0x7fffu + ((v.u >> 16) & 1u);
    return (unsigned short)(r >> 16);
}

// pack two fp32 -> packed bf16x2 (v_cvt_pk_bf16_f32 on gfx950)
__device__ inline unsigned int pk_bf16(float a, float b) {
#if __has_builtin(__builtin_amdgcn_cvt_pk_bf16_f32)
    typedef __attribute__((ext_vector_type(2))) __bf16 bf16x2;
    bf16x2 v = __builtin_amdgcn_cvt_pk_bf16_f32(a, b);
    return __builtin_bit_cast(unsigned int, v);
#else
    return (unsigned)f2bf(a) | ((unsigned)f2bf(b) << 16);
#endif
}

// async 16B global -> LDS (wave-uniform LDS base + lane*16)
__device__ inline void async_ld16(const void* g, void* lds) {
    __builtin_amdgcn_global_load_lds(
        (const __attribute__((address_space(1))) unsigned int*)g,
        (__attribute__((address_space(3))) unsigned int*)lds, 16, 0, 0);
}

#define MFMA_BF16 __builtin_amdgcn_mfma_f32_16x16x32_bf16

// ---------------------------------------------------------------------------
// Merged prep: bid<8192 -> x fp32->bf16 convert; else 32x32 transpose-convert
// of w_qkv (128 col-tiles) / w_proj (32 col-tiles) into [n][k] bf16.
// (unchanged; passing)
// ---------------------------------------------------------------------------
__global__ __launch_bounds__(256) void prep_all(
    const float* __restrict__ x, const float* __restrict__ w_qkv,
    const float* __restrict__ w_proj,
    unsigned short* __restrict__ xb, unsigned short* __restrict__ wqkvT,
    unsigned short* __restrict__ wprojT)
{
    const int bid = blockIdx.x;
    if (bid < 8192) {
        int i = (bid * 256 + threadIdx.x) * 4;
        float4 v = *(const float4*)(x + i);
        uint2 o;
        o.x = pk_bf16(v.x, v.y);
        o.y = pk_bf16(v.z, v.w);
        *(uint2*)(xb + i) = o;
        return;
    }
    __shared__ float tile[32][33];
    const int tt = bid - 8192;          // 0..4095
    int bx = tt & 127;                  // col tile
    const int by = tt >> 7;             // row tile (0..31)
    const float* src; unsigned short* dst; int Cc;
    if (bx < 96) { src = w_qkv;  dst = wqkvT;  Cc = 3072; }
    else         { src = w_proj; dst = wprojT; Cc = 1024; bx -= 96; }
    const int tx = threadIdx.x & 31, ty = threadIdx.x >> 5;
    #pragma unroll
    for (int r = 0; r < 32; r += 8)
        tile[ty + r][tx] = src[(size_t)(by*32 + ty + r) * Cc + bx*32 + tx];
    __syncthreads();
    #pragma unroll
    for (int r = 0; r < 32; r += 8)
        dst[(size_t)(bx*32 + ty + r) * 1024 + by*32 + tx] = f2bf(tile[tx][ty + r]);
}

// ---------------------------------------------------------------------------
// QKV GEMM v7 (resubmission; R10 failure was infra, same signature as R4
// which passed on identical resubmission in R5).  BIGGER TILE, same proven
// sync structure.  R5/R6/R9 ladder showed perf scales with MFMA per
// barrier-pair (R6: 32/pair = 71.6us; R9: 16/pair = 97.8us).  v7: 256x128
// tile per block (wave = 128x64, acc[8][4]) -> 64 MFMA per barrier-pair.
// Single-buffered 48KB static LDS (A 256x64 = 32KB + B 128x64 = 16KB),
// serial stage -> __syncthreads -> compute -> __syncthreads (R5's loop).
// Same 128B-row XOR-swizzled layout (measured 0 conflicts), same epilogue
// numerics with wm*64 -> wm*128 and mi<8.
// Grid: 768 = 8 xcd x 4 m_l x 24 n (XCD-affine 2MB A-slices).
// ---------------------------------------------------------------------------
__global__ __launch_bounds__(256) void gemm_qkv(
    const unsigned short* __restrict__ A,   // [8192][1024] bf16
    const unsigned short* __restrict__ BT,  // [3072][1024] bf16
    const float* __restrict__ bias,         // [3072] fp32
    unsigned short* __restrict__ qb, unsigned short* __restrict__ kb,
    unsigned short* __restrict__ vtb)
{
    __shared__ unsigned short As[256 * 64];   // 32KB, 128B rows
    __shared__ unsigned short Bs[128 * 64];   // 16KB
    const int tid = threadIdx.x;
    const int wave = tid >> 6, lane = tid & 63;
    const int wm = wave >> 1, wn = wave & 1;
    const int l15 = lane & 15, lq = lane >> 4;
    const int bid = blockIdx.x;
    const int xcd = bid & 7, idx = bid >> 3;         // idx: 0..95
    const int m0 = (xcd * 4 + (idx & 3)) * 256;      // 32 m-tiles
    const int n0 = (idx >> 2) * 128;                 // 24 n-tiles
    const int sel = n0 >> 10;                        // 0=q 1=k 2=v
    const int row8 = lane >> 3;                      // 0..7
    const int chx8 = ((lane & 7) ^ row8) * 8;        // XOR-swizzled src chunk
    const int cxa = l15 & 7;                         // read-side XOR key

    f32x4 acc[8][4] = {};

    for (int k0 = 0; k0 < 1024; k0 += 64) {
        // stage 256x64 A (8 calls/wave) + 128x64 B (4 calls/wave)
        #pragma unroll
        for (int c = 0; c < 8; ++c) {
            const int r = wave*64 + c*8;
            async_ld16(A + (size_t)(m0 + r + row8)*1024 + k0 + chx8,
                       (char*)As + r*128);
        }
        #pragma unroll
        for (int c = 0; c < 4; ++c) {
            const int r = wave*32 + c*8;
            async_ld16(BT + (size_t)(n0 + r + row8)*1024 + k0 + chx8,
                       (char*)Bs + r*128);
        }
        __syncthreads();    // per-wave vmcnt(0) drain + barrier: tiles ready
        #pragma unroll
        for (int ks = 0; ks < 2; ++ks) {
            short8 af[8], bf[4];
            #pragma unroll
            for (int i = 0; i < 8; ++i)
                af[i] = *(const short8*)&As[(wm*128 + i*16 + l15) * 64
                                            + (((ks*4 + lq) ^ cxa) << 3)];
            #pragma unroll
            for (int j = 0; j < 4; ++j)
                bf[j] = *(const short8*)&Bs[(wn*64 + j*16 + l15) * 64
                                            + (((ks*4 + lq) ^ cxa) << 3)];
            if (sel < 2) {
                #pragma unroll
                for (int mi = 0; mi < 8; ++mi)
                    #pragma unroll
                    for (int ni = 0; ni < 4; ++ni)
                        acc[mi][ni] = MFMA_BF16(bf[ni], af[mi], acc[mi][ni], 0, 0, 0);
            } else {
                #pragma unroll
                for (int mi = 0; mi < 8; ++mi)
                    #pragma unroll
                    for (int ni = 0; ni < 4; ++ni)
                        acc[mi][ni] = MFMA_BF16(af[mi], bf[ni], acc[mi][ni], 0, 0, 0);
            }
        }
        __syncthreads();    // reads retired before next stage overwrites
    }

    if (sel < 2) {
        // lane l15 -> t; reg r -> d. 4 consecutive d per lane -> 8B store.
        const float qs = (sel == 0) ? 0.180336880f : 1.0f;  // 0.125*log2(e) | 1
        unsigned short* dst = (sel == 0) ? qb : kb;
        #pragma unroll
        for (int mi = 0; mi < 8; ++mi) {
            const int t = m0 + wm*128 + mi*16 + l15;
            const int bb = t >> 11, tt = t & 2047;
            #pragma unroll
            for (int ni = 0; ni < 4; ++ni) {
                const int nb = n0 + wn*64 + ni*16 + lq*4;
                const int hh = (nb >> 6) & 15, d0 = nb & 63;
                float4 bv = *(const float4*)(bias + nb);
                float v0 = (acc[mi][ni][0] + bv.x) * qs;
                float v1 = (acc[mi][ni][1] + bv.y) * qs;
                float v2 = (acc[mi][ni][2] + bv.z) * qs;
                float v3 = (acc[mi][ni][3] + bv.w) * qs;
                uint2 pk; pk.x = pk_bf16(v0, v1); pk.y = pk_bf16(v2, v3);
                *(uint2*)(dst + ((size_t)(bb*16 + hh)*2048 + tt)*64 + d0) = pk;
            }
        }
    } else {
        // lane l15 -> d; reg r -> t. 4 consecutive t per lane -> 8B store.
        // column permuted within each 64-tile: t' = c<<5 | lq2<<3 | h<<2 | r
        #pragma unroll
        for (int mi = 0; mi < 8; ++mi) {
            const int t0 = m0 + wm*128 + mi*16 + lq*4;
            const int bb = t0 >> 11, tt = t0 & 2047;
            const int tl = tt & 63;
            const int tp = (tt & ~63) | (tl & 32) | ((tl & 12) << 1) | ((tl & 16) >> 2);
            #pragma unroll
            for (int ni = 0; ni < 4; ++ni) {
                const int n = n0 + wn*64 + ni*16 + l15;
                const int hh = (n >> 6) & 15, d = n & 63;
                const float bs = bias[n];
                uint2 pk;
                pk.x = pk_bf16(acc[mi][ni][0] + bs, acc[mi][ni][1] + bs);
                pk.y = pk_bf16(acc[mi][ni][2] + bs, acc[mi][ni][3] + bs);
                *(uint2*)(vtb + ((size_t)(bb*16 + hh)*64 + d)*2048 + tp) = pk;
            }
        }
    }
}

// ---------------------------------------------------------------------------
// Output projection GEMM (round-6 version, part of the 238us build):
// 128x128 tile, BK=64, double-buffered 64KB LDS, prefetch-before-compute,
// __syncthreads-only sync; swapped operands -> float4 coalesced stores.
// Grid: 512 = 8 xcd x 8 m_l x 8 n.
// ---------------------------------------------------------------------------
__global__ __launch_bounds__(256) void gemm_proj(
    const unsigned short* __restrict__ A,   // [8192][1024] bf16
    const unsigned short* __restrict__ BT,  // [1024][1024] bf16
    const float* __restrict__ bias,         // [1024]
    float* __restrict__ out)
{
    __shared__ unsigned short As[2][128 * 64];
    __shared__ unsigned short Bs[2][128 * 64];
    const int tid = threadIdx.x;
    const int wave = tid >> 6, lane = tid & 63;
    const int wm = wave >> 1, wn = wave & 1;
    const int l15 = lane & 15, lq = lane >> 4;
    const int bid = blockIdx.x;
    const int xcd = bid & 7, idx = bid >> 3;         // idx: 0..63
    const int m0 = (xcd * 8 + (idx & 7)) * 128;      // 64 m-tiles
    const int n0 = (idx >> 3) * 128;                 // 8 n-tiles
    const int row8 = lane >> 3;
    const int chx8 = ((lane & 7) ^ row8) * 8;
    const int cxa = l15 & 7;

    f32x4 acc[4][4] = {};

#define PSTAGE(buf, K0) do { _Pragma("unroll") \
    for (int c = 0; c < 4; ++c) { \
        const int r = wave*32 + c*8; \
        async_ld16(A  + (size_t)(m0 + r + row8)*1024 + (K0) + chx8, \
                   (char*)&As[buf][0] + r*128); \
        async_ld16(BT + (size_t)(n0 + r + row8)*1024 + (K0) + chx8, \
                   (char*)&Bs[buf][0] + r*128); \
    } } while (0)

    PSTAGE(0, 0);
    __syncthreads();

    for (int t = 0; t < 16; ++t) {
        const int cur = t & 1;
        if (t < 15) PSTAGE(cur ^ 1, (t + 1) << 6);
        const unsigned short* Ac = &As[cur][0];
        const unsigned short* Bc = &Bs[cur][0];
        #pragma unroll
        for (int ks = 0; ks < 2; ++ks) {
            short8 af[4], bf[4];
            #pragma unroll
            for (int i = 0; i < 4; ++i) {
                const int ra = wm*64 + i*16 + l15;
                const int rb = wn*64 + i*16 + l15;
                af[i] = *(const short8*)&Ac[ra*64 + (((ks*4 + lq) ^ cxa) << 3)];
                bf[i] = *(const short8*)&Bc[rb*64 + (((ks*4 + lq) ^ cxa) << 3)];
            }
            #pragma unroll
            for (int mi = 0; mi < 4; ++mi)
                #pragma unroll
                for (int ni = 0; ni < 4; ++ni)
                    acc[mi][ni] = MFMA_BF16(bf[ni], af[mi], acc[mi][ni], 0, 0, 0);
        }
        __syncthreads();
    }
#undef PSTAGE

    #pragma unroll
    for (int mi = 0; mi < 4; ++mi) {
        const int m = m0 + wm*64 + mi*16 + l15;
        #pragma unroll
        for (int ni = 0; ni < 4; ++ni) {
            const int nb = n0 + wn*64 + ni*16 + lq*4;
            float4 bv = *(const float4*)(bias + nb);
            float4 o;
            o.x = acc[mi][ni][0] + bv.x;
            o.y = acc[mi][ni][1] + bv.y;
            o.z = acc[mi][ni][2] + bv.z;
            o.w = acc[mi][ni][3] + bv.w;
            *(float4*)(out + (size_t)m * 1024 + nb) = o;
        }
    }
}

// ---------------------------------------------------------------------------
// MFMA flash attention v5 (byte-identical to the passing build): no-max
// exp2 softmax, 4 waves split k-tiles, private K/V LDS regions, counted-
// vmcnt pipeline, no barriers in main loop, P stays in registers (swapped
// QK^T + pre-permuted V layout).  Cross-wave o/l combine at end.
// ---------------------------------------------------------------------------
__global__ __launch_bounds__(256, 2) void attn_mfma(
    const unsigned short* __restrict__ qb,   // [B,H,T,D]
    const unsigned short* __restrict__ kb,   // [B,H,T,D]
    const unsigned short* __restrict__ vtb,  // [B,H,D,T'] (64-tile permuted)
    unsigned short* __restrict__ ab)         // [B*T][C]
{
    extern __shared__ unsigned char smem[];  // 4 x 16KB wave regions = 64KB
    const int tid  = threadIdx.x;
    const int wave = tid >> 6, lane = tid & 63;
    const int l15  = lane & 15, lq = lane >> 4;
    const int linear = blockIdx.x;
    const int xc  = linear & 7;            // XCD class
    const int idx = linear >> 3;
    const int bh  = xc * 8 + (idx & 7);    // 8 bh per XCD class
    const int qblk = 31 - (idx >> 3);      // heavy q-tiles dispatch first
    const int q0 = qblk * 64;
    const int b = bh >> 4, h = bh & 15;
    const size_t base = (size_t)bh * 2048 * 64;

    unsigned short* Kw = (unsigned short*)(smem + wave * 16384);  // 8KB
    unsigned short* Vw = Kw + 4096;                               // 8KB

    const int row8 = lane >> 3;                 // 0..7
    const int chx8 = ((lane & 7) ^ row8) * 8;   // XOR-swizzled source chunk

#define STAGE_K(J0) do { _Pragma("unroll") for (int op = 0; op < 8; ++op) \
    async_ld16(kb + base + (size_t)((J0) + op*8 + row8)*64 + chx8, \
               (char*)Kw + op*1024); } while (0)
#define STAGE_V(J0) do { _Pragma("unroll") for (int op = 0; op < 8; ++op) \
    async_ld16(vtb + base + (size_t)(op*8 + row8)*2048 + (J0) + chx8, \
               (char*)Vw + op*1024); } while (0)

    // Q fragments (B-operand), hoisted to registers: qf[ks][nq]
    short8 qf[2][4];
    #pragma unroll
    for (int ks = 0; ks < 2; ++ks)
        #pragma unroll
        for (int nq = 0; nq < 4; ++nq)
            qf[ks][nq] = *(const short8*)(qb + base
                + (size_t)(q0 + nq*16 + l15)*64 + ks*32 + lq*8);

    f32x4 o[4][4] = {};          // [nq][nd]: q=nq*16+lq*4+r, d=nd*16+l15
    float lacc[4] = {0.f, 0.f, 0.f, 0.f};

    const int jfirst = wave * 64;
    const int nt = (qblk >= wave) ? ((qblk - wave) >> 2) + 1 : 0;

    if (nt > 0) { STAGE_K(jfirst); STAGE_V(jfirst); }

    for (int i = 0; i < nt; ++i) {
        const int j0 = jfirst + i * 256;
        const bool more = (i + 1 < nt);

        // K(t) ready (V(t)'s 8 loads remain outstanding)
        asm volatile("s_waitcnt vmcnt(8)" ::: "memory");

        // ---- QK^T (swapped): s[ni][nq], k=ni*16+lq*4+r, q=nq*16+l15 ----
        short8 kf0[4], kf1[4];
        #pragma unroll
        for (int ni = 0; ni < 4; ++ni) {
            const unsigned short* kr = Kw + (ni*16 + l15) * 64;
            kf0[ni] = *(const short8*)(kr + (((0*4 + lq) ^ (l15 & 7)) << 3));
            kf1[ni] = *(const short8*)(kr + (((1*4 + lq) ^ (l15 & 7)) << 3));
        }
        f32x4 s[4][4] = {};
        #pragma unroll
        for (int ni = 0; ni < 4; ++ni)
            #pragma unroll
            for (int nq = 0; nq < 4; ++nq) {
                s[ni][nq] = MFMA_BF16(kf0[ni], qf[0][nq], s[ni][nq], 0, 0, 0);
                s[ni][nq] = MFMA_BF16(kf1[ni], qf[1][nq], s[ni][nq], 0, 0, 0);
            }
        // K reads retired -> safe to overwrite K buffer with next tile
        asm volatile("s_waitcnt lgkmcnt(0)" ::: "memory");
        if (more) STAGE_K(j0 + 256);

        // ---- causal mask (diagonal tile only) ----
        if (j0 == q0) {
            #pragma unroll
            for (int ni = 0; ni < 4; ++ni)
                #pragma unroll
                for (int nq = 0; nq < 4; ++nq)
                    #pragma unroll
                    for (int r = 0; r < 4; ++r)
                        if (ni*16 + lq*4 + r > nq*16 + l15)
                            s[ni][nq][r] = -1e30f;
        }

        // ---- p = exp2(s); pack PV A-fragments in-lane; accumulate l ----
        short8 pf[2][4];
        #pragma unroll
        for (int c = 0; c < 2; ++c)
            #pragma unroll
            for (int nq = 0; nq < 4; ++nq) {
                float p0 = __builtin_amdgcn_exp2f(s[2*c  ][nq][0]);
                float p1 = __builtin_amdgcn_exp2f(s[2*c  ][nq][1]);
                float p2 = __builtin_amdgcn_exp2f(s[2*c  ][nq][2]);
                float p3 = __builtin_amdgcn_exp2f(s[2*c  ][nq][3]);
                float p4 = __builtin_amdgcn_exp2f(s[2*c+1][nq][0]);
                float p5 = __builtin_amdgcn_exp2f(s[2*c+1][nq][1]);
                float p6 = __builtin_amdgcn_exp2f(s[2*c+1][nq][2]);
                float p7 = __builtin_amdgcn_exp2f(s[2*c+1][nq][3]);
                lacc[nq] += ((p0 + p1) + (p2 + p3)) + ((p4 + p5) + (p6 + p7));
                uint4 pu;
                pu.x = pk_bf16(p0, p1); pu.y = pk_bf16(p2, p3);
                pu.z = pk_bf16(p4, p5); pu.w = pk_bf16(p6, p7);
                pf[c][nq] = __builtin_bit_cast(short8, pu);
            }

        // V(t) ready (K(t+1) outstanding if issued)
        if (more) asm volatile("s_waitcnt vmcnt(8)" ::: "memory");
        else      asm volatile("s_waitcnt vmcnt(0)" ::: "memory");

        // ---- PV: o[nq][nd] += pf[c][nq] x vf[c][nd] ----
        #pragma unroll
        for (int c = 0; c < 2; ++c) {
            short8 vf[4];
            #pragma unroll
            for (int nd = 0; nd < 4; ++nd)
                vf[nd] = *(const short8*)(Vw + (nd*16 + l15) * 64
                    + (((c*4 + lq) ^ (l15 & 7)) << 3));
            #pragma unroll
            for (int nq = 0; nq < 4; ++nq)
                #pragma unroll
                for (int nd = 0; nd < 4; ++nd)
                    o[nq][nd] = MFMA_BF16(pf[c][nq], vf[nd], o[nq][nd], 0, 0, 0);
        }
        // V reads retired -> safe to overwrite V buffer
        asm volatile("s_waitcnt lgkmcnt(0)" ::: "memory");
        if (more) STAGE_V(j0 + 256);
    }
#undef STAGE_K
#undef STAGE_V

    // ---- cross-wave combine ----
    // 1) per-wave l partials (reduce over lq groups), store 64 f32 per region
    #pragma unroll
    for (int nq = 0; nq < 4; ++nq) {
        float t = lacc[nq];
        t += __shfl_xor(t, 16);
        t += __shfl_xor(t, 32);
        if (lq == 0) ((float*)Kw)[nq*16 + l15] = t;
    }
    __syncthreads();
    // 2) each thread computes linv for its 16 q rows (qg = wave)
    const int qg = wave, d = lane;
    f32x4 linv4[4];
    #pragma unroll
    for (int j = 0; j < 4; ++j) {
        f32x4 lsum = {};
        #pragma unroll
        for (int w2 = 0; w2 < 4; ++w2)
            lsum += *(const f32x4*)((const float*)(smem + w2*16384) + qg*16 + j*4);
        #pragma unroll
        for (int r = 0; r < 4; ++r)
            linv4[j][r] = __builtin_amdgcn_rcpf(lsum[r]);
    }
    __syncthreads();
    // 3) write O partials (rotated cols: col = (q + 4*(d&15)) & 63)
    #pragma unroll
    for (int nq = 0; nq < 4; ++nq)
        #pragma unroll
        for (int nd = 0; nd < 4; ++nd) {
            const int row = nd*16 + l15;
            const int col = (nq*16 + lq*4 + 4*l15) & 63;
            *(f32x4*)((float*)Kw + row*64 + col) = o[nq][nd];
        }
    __syncthreads();
    // 4) sum 4 partials, normalize, store bf16 (coalesced 128B per wave-store)
    #pragma unroll
    for (int j = 0; j < 4; ++j) {
        const int colb = (qg*16 + j*4 + 4*(d & 15)) & 63;
        f32x4 acc = {};
        #pragma unroll
        for (int w2 = 0; w2 < 4; ++w2)
            acc += *(const f32x4*)((const float*)(smem + w2*16384) + d*64 + colb);
        #pragma unroll
        for (int r = 0; r < 4; ++r) {
            const int q = qg*16 + j*4 + r;
            ab[(size_t)(b*2048 + q0 + q)*1024 + h*64 + d] = f2bf(acc[r] * linv4[j][r]);
        }
    }
}

extern "C" void kernel_launch(void* const* d_in, const int* in_sizes, int n_in,
                              void* d_out, int out_size, void* d_ws, size_t ws_size,
                              hipStream_t stream) {
    const float* x      = (const float*)d_in[0];   // [B,T,C]
    const float* w_qkv  = (const float*)d_in[1];   // [C,3C]
    const float* b_qkv  = (const float*)d_in[2];   // [3C]
    const float* w_proj = (const float*)d_in[3];   // [C,C]
    const float* b_proj = (const float*)d_in[4];   // [C]
    float* out = (float*)d_out;                    // [B,T,C] fp32

    unsigned short* xb     = (unsigned short*)d_ws;          // 8192*1024
    unsigned short* wqkvT  = xb + 8388608;                   // 3072*1024
    unsigned short* wprojT = wqkvT + 3145728;                // 1024*1024
    unsigned short* qbuf   = wprojT + 1048576;               // [B,H,T,D]
    unsigned short* kbuf   = qbuf + 8388608;                 // [B,H,T,D]
    unsigned short* vtbuf  = kbuf + 8388608;                 // [B,H,D,T']
    unsigned short* abuf   = vtbuf + 8388608;                // [B*T][C]
    // total: 46,137,344 bf16 elems = 92 MiB

    prep_all<<<12288, 256, 0, stream>>>(x, w_qkv, w_proj, xb, wqkvT, wprojT);
    gemm_qkv<<<768, 256, 0, stream>>>(xb, wqkvT, b_qkv, qbuf, kbuf, vtbuf);
    attn_mfma<<<2048, 256, 65536, stream>>>(qbuf, kbuf, vtbuf, abuf);
    gemm_proj<<<512, 256, 0, stream>>>(abuf, wprojT, b_proj, out);
}

// Round 12
// 242.904 us; speedup vs baseline: 1.1131x; 1.0728x over previous
//
#include <hip/hip_runtime.h>

#define B_ 4
#define T_ 2048
#define C_ 1024
#define H_ 16
#define D_ 64

typedef __attribute__((ext_vector_type(8))) short short8;
typedef __attribute__((ext_vector_type(4))) float f32x4;

// float -> bf16 round-to-nearest-even (fallback)
__device__ inline unsigned short f2bf(float f) {
    union { float f; unsigned u; } v; v.f = f;
    unsigned r = v.u + 0x7fffu + ((v.u >> 16) & 1u);
    return (unsigned short)(r >> 16);
}

// pack two fp32 -> packed bf16x2 (v_cvt_pk_bf16_f32 on gfx950)
__device__ inline unsigned int pk_bf16(float a, float b) {
#if __has_builtin(__builtin_amdgcn_cvt_pk_bf16_f32)
    typedef __attribute__((ext_vector_type(2))) __bf16 bf16x2;
    bf16x2 v = __builtin_amdgcn_cvt_pk_bf16_f32(a, b);
    return __builtin_bit_cast(unsigned int, v);
#else
    return (unsigned)f2bf(a) | ((unsigned)f2bf(b) << 16);
#endif
}

// async 16B global -> LDS (wave-uniform LDS base + lane*16)
__device__ inline void async_ld16(const void* g, void* lds) {
    __builtin_amdgcn_global_load_lds(
        (const __attribute__((address_space(1))) unsigned int*)g,
        (__attribute__((address_space(3))) unsigned int*)lds, 16, 0, 0);
}

#define MFMA_BF16 __builtin_amdgcn_mfma_f32_16x16x32_bf16

// ---------------------------------------------------------------------------
// Merged prep: bid<8192 -> x fp32->bf16 convert; else 32x32 transpose-convert
// of w_qkv (128 col-tiles) / w_proj (32 col-tiles) into [n][k] bf16.
// (unchanged; passing)
// ---------------------------------------------------------------------------
__global__ __launch_bounds__(256) void prep_all(
    const float* __restrict__ x, const float* __restrict__ w_qkv,
    const float* __restrict__ w_proj,
    unsigned short* __restrict__ xb, unsigned short* __restrict__ wqkvT,
    unsigned short* __restrict__ wprojT)
{
    const int bid = blockIdx.x;
    if (bid < 8192) {
        int i = (bid * 256 + threadIdx.x) * 4;
        float4 v = *(const float4*)(x + i);
        uint2 o;
        o.x = pk_bf16(v.x, v.y);
        o.y = pk_bf16(v.z, v.w);
        *(uint2*)(xb + i) = o;
        return;
    }
    __shared__ float tile[32][33];
    const int tt = bid - 8192;          // 0..4095
    int bx = tt & 127;                  // col tile
    const int by = tt >> 7;             // row tile (0..31)
    const float* src; unsigned short* dst; int Cc;
    if (bx < 96) { src = w_qkv;  dst = wqkvT;  Cc = 3072; }
    else         { src = w_proj; dst = wprojT; Cc = 1024; bx -= 96; }
    const int tx = threadIdx.x & 31, ty = threadIdx.x >> 5;
    #pragma unroll
    for (int r = 0; r < 32; r += 8)
        tile[ty + r][tx] = src[(size_t)(by*32 + ty + r) * Cc + bx*32 + tx];
    __syncthreads();
    #pragma unroll
    for (int r = 0; r < 32; r += 8)
        dst[(size_t)(bx*32 + ty + r) * 1024 + by*32 + tx] = f2bf(tile[tx][ty + r]);
}

// ---------------------------------------------------------------------------
// QKV GEMM (round-6 version, the proven family optimum): 128x128 tile,
// 256 threads, BK=64, 128B-row XOR-swizzled LDS (0 conflicts measured),
// double-buffered 64KB, prefetch-before-compute, __syncthreads-only sync.
// Family ladder (measured): R9 16 MFMA/pair = 97.8us; R5 serial = 73.3us;
// R6 dbuf = 71.6us; v7 64/pair @1blk/CU = 90us.  R6 is the optimum.
// Grid: 1536 = 8 xcd x 8 m_l x 24 n (XCD-affine A-slices).
// ---------------------------------------------------------------------------
__global__ __launch_bounds__(256) void gemm_qkv(
    const unsigned short* __restrict__ A,   // [8192][1024] bf16
    const unsigned short* __restrict__ BT,  // [3072][1024] bf16
    const float* __restrict__ bias,         // [3072] fp32
    unsigned short* __restrict__ qb, unsigned short* __restrict__ kb,
    unsigned short* __restrict__ vtb)
{
    __shared__ unsigned short As[2][128 * 64];   // 2 x 16KB, 128B rows
    __shared__ unsigned short Bs[2][128 * 64];   // 2 x 16KB
    const int tid = threadIdx.x;
    const int wave = tid >> 6, lane = tid & 63;
    const int wm = wave >> 1, wn = wave & 1;
    const int l15 = lane & 15, lq = lane >> 4;
    const int bid = blockIdx.x;
    const int xcd = bid & 7, idx = bid >> 3;         // idx: 0..191
    const int m0 = (xcd * 8 + (idx & 7)) * 128;      // 64 m-tiles
    const int n0 = (idx >> 3) * 128;                 // 24 n-tiles
    const int sel = n0 >> 10;                        // 0=q 1=k 2=v
    const int row8 = lane >> 3;                      // 0..7
    const int chx8 = ((lane & 7) ^ row8) * 8;        // XOR-swizzled src chunk
    const int cxa = l15 & 7;                         // read-side XOR key

    f32x4 acc[4][4] = {};

#define STAGE(buf, K0) do { _Pragma("unroll") \
    for (int c = 0; c < 4; ++c) { \
        const int r = wave*32 + c*8; \
        async_ld16(A  + (size_t)(m0 + r + row8)*1024 + (K0) + chx8, \
                   (char*)&As[buf][0] + r*128); \
        async_ld16(BT + (size_t)(n0 + r + row8)*1024 + (K0) + chx8, \
                   (char*)&Bs[buf][0] + r*128); \
    } } while (0)

    STAGE(0, 0);
    __syncthreads();                       // buf0 ready

    for (int t = 0; t < 16; ++t) {
        const int cur = t & 1;
        if (t < 15) STAGE(cur ^ 1, (t + 1) << 6);   // prefetch under compute
        const unsigned short* Ac = &As[cur][0];
        const unsigned short* Bc = &Bs[cur][0];
        #pragma unroll
        for (int ks = 0; ks < 2; ++ks) {
            short8 af[4], bf[4];
            #pragma unroll
            for (int i = 0; i < 4; ++i) {
                const int ra = wm*64 + i*16 + l15;
                const int rb = wn*64 + i*16 + l15;
                af[i] = *(const short8*)&Ac[ra*64 + (((ks*4 + lq) ^ cxa) << 3)];
                bf[i] = *(const short8*)&Bc[rb*64 + (((ks*4 + lq) ^ cxa) << 3)];
            }
            if (sel < 2) {
                #pragma unroll
                for (int mi = 0; mi < 4; ++mi)
                    #pragma unroll
                    for (int ni = 0; ni < 4; ++ni)
                        acc[mi][ni] = MFMA_BF16(bf[ni], af[mi], acc[mi][ni], 0, 0, 0);
            } else {
                #pragma unroll
                for (int mi = 0; mi < 4; ++mi)
                    #pragma unroll
                    for (int ni = 0; ni < 4; ++ni)
                        acc[mi][ni] = MFMA_BF16(af[mi], bf[ni], acc[mi][ni], 0, 0, 0);
            }
        }
        __syncthreads();   // publishes buf[t+1] (vmcnt drain) + retires reads
    }
#undef STAGE

    if (sel < 2) {
        // lane l15 -> t; reg r -> d. 4 consecutive d per lane -> 8B store.
        const float qs = (sel == 0) ? 0.180336880f : 1.0f;  // 0.125*log2(e) | 1
        unsigned short* dst = (sel == 0) ? qb : kb;
        #pragma unroll
        for (int mi = 0; mi < 4; ++mi) {
            const int t = m0 + wm*64 + mi*16 + l15;
            const int bb = t >> 11, tt = t & 2047;
            #pragma unroll
            for (int ni = 0; ni < 4; ++ni) {
                const int nb = n0 + wn*64 + ni*16 + lq*4;
                const int hh = (nb >> 6) & 15, d0 = nb & 63;
                float4 bv = *(const float4*)(bias + nb);
                float v0 = (acc[mi][ni][0] + bv.x) * qs;
                float v1 = (acc[mi][ni][1] + bv.y) * qs;
                float v2 = (acc[mi][ni][2] + bv.z) * qs;
                float v3 = (acc[mi][ni][3] + bv.w) * qs;
                uint2 pk; pk.x = pk_bf16(v0, v1); pk.y = pk_bf16(v2, v3);
                *(uint2*)(dst + ((size_t)(bb*16 + hh)*2048 + tt)*64 + d0) = pk;
            }
        }
    } else {
        // lane l15 -> d; reg r -> t. 4 consecutive t per lane -> 8B store.
        // column permuted within each 64-tile: t' = c<<5 | lq2<<3 | h<<2 | r
        #pragma unroll
        for (int mi = 0; mi < 4; ++mi) {
            const int t0 = m0 + wm*64 + mi*16 + lq*4;
            const int bb = t0 >> 11, tt = t0 & 2047;
            const int tl = tt & 63;
            const int tp = (tt & ~63) | (tl & 32) | ((tl & 12) << 1) | ((tl & 16) >> 2);
            #pragma unroll
            for (int ni = 0; ni < 4; ++ni) {
                const int n = n0 + wn*64 + ni*16 + l15;
                const int hh = (n >> 6) & 15, d = n & 63;
                const float bs = bias[n];
                uint2 pk;
                pk.x = pk_bf16(acc[mi][ni][0] + bs, acc[mi][ni][1] + bs);
                pk.y = pk_bf16(acc[mi][ni][2] + bs, acc[mi][ni][3] + bs);
                *(uint2*)(vtb + ((size_t)(bb*16 + hh)*64 + d)*2048 + tp) = pk;
            }
        }
    }
}

// ---------------------------------------------------------------------------
// Output projection GEMM (round-6 version): 128x128 tile, BK=64, double-
// buffered 64KB LDS, prefetch-before-compute, __syncthreads-only sync;
// swapped operands -> float4 coalesced stores.  Grid: 512 = 8x8x8.
// ---------------------------------------------------------------------------
__global__ __launch_bounds__(256) void gemm_proj(
    const unsigned short* __restrict__ A,   // [8192][1024] bf16
    const unsigned short* __restrict__ BT,  // [1024][1024] bf16
    const float* __restrict__ bias,         // [1024]
    float* __restrict__ out)
{
    __shared__ unsigned short As[2][128 * 64];
    __shared__ unsigned short Bs[2][128 * 64];
    const int tid = threadIdx.x;
    const int wave = tid >> 6, lane = tid & 63;
    const int wm = wave >> 1, wn = wave & 1;
    const int l15 = lane & 15, lq = lane >> 4;
    const int bid = blockIdx.x;
    const int xcd = bid & 7, idx = bid >> 3;         // idx: 0..63
    const int m0 = (xcd * 8 + (idx & 7)) * 128;      // 64 m-tiles
    const int n0 = (idx >> 3) * 128;                 // 8 n-tiles
    const int row8 = lane >> 3;
    const int chx8 = ((lane & 7) ^ row8) * 8;
    const int cxa = l15 & 7;

    f32x4 acc[4][4] = {};

#define PSTAGE(buf, K0) do { _Pragma("unroll") \
    for (int c = 0; c < 4; ++c) { \
        const int r = wave*32 + c*8; \
        async_ld16(A  + (size_t)(m0 + r + row8)*1024 + (K0) + chx8, \
                   (char*)&As[buf][0] + r*128); \
        async_ld16(BT + (size_t)(n0 + r + row8)*1024 + (K0) + chx8, \
                   (char*)&Bs[buf][0] + r*128); \
    } } while (0)

    PSTAGE(0, 0);
    __syncthreads();

    for (int t = 0; t < 16; ++t) {
        const int cur = t & 1;
        if (t < 15) PSTAGE(cur ^ 1, (t + 1) << 6);
        const unsigned short* Ac = &As[cur][0];
        const unsigned short* Bc = &Bs[cur][0];
        #pragma unroll
        for (int ks = 0; ks < 2; ++ks) {
            short8 af[4], bf[4];
            #pragma unroll
            for (int i = 0; i < 4; ++i) {
                const int ra = wm*64 + i*16 + l15;
                const int rb = wn*64 + i*16 + l15;
                af[i] = *(const short8*)&Ac[ra*64 + (((ks*4 + lq) ^ cxa) << 3)];
                bf[i] = *(const short8*)&Bc[rb*64 + (((ks*4 + lq) ^ cxa) << 3)];
            }
            #pragma unroll
            for (int mi = 0; mi < 4; ++mi)
                #pragma unroll
                for (int ni = 0; ni < 4; ++ni)
                    acc[mi][ni] = MFMA_BF16(bf[ni], af[mi], acc[mi][ni], 0, 0, 0);
        }
        __syncthreads();
    }
#undef PSTAGE

    #pragma unroll
    for (int mi = 0; mi < 4; ++mi) {
        const int m = m0 + wm*64 + mi*16 + l15;
        #pragma unroll
        for (int ni = 0; ni < 4; ++ni) {
            const int nb = n0 + wn*64 + ni*16 + lq*4;
            float4 bv = *(const float4*)(bias + nb);
            float4 o;
            o.x = acc[mi][ni][0] + bv.x;
            o.y = acc[mi][ni][1] + bv.y;
            o.z = acc[mi][ni][2] + bv.z;
            o.w = acc[mi][ni][3] + bv.w;
            *(float4*)(out + (size_t)m * 1024 + nb) = o;
        }
    }
}

// ---------------------------------------------------------------------------
// MFMA flash attention v6: round-1 v5 structure (proven since round 1) with
// ONE addition: s_setprio(1/0) around the two MFMA clusters (T5).  attn's
// waves run independent counted-vmcnt pipelines with NO lockstep barriers —
// exactly the role-diverse regime where m191 measured +4-7% from setprio
// (vs 0% on barrier-locked GEMMs).  VGPR=48 -> no spill risk; no layout or
// sync change.
// ---------------------------------------------------------------------------
__global__ __launch_bounds__(256, 2) void attn_mfma(
    const unsigned short* __restrict__ qb,   // [B,H,T,D]
    const unsigned short* __restrict__ kb,   // [B,H,T,D]
    const unsigned short* __restrict__ vtb,  // [B,H,D,T'] (64-tile permuted)
    unsigned short* __restrict__ ab)         // [B*T][C]
{
    extern __shared__ unsigned char smem[];  // 4 x 16KB wave regions = 64KB
    const int tid  = threadIdx.x;
    const int wave = tid >> 6, lane = tid & 63;
    const int l15  = lane & 15, lq = lane >> 4;
    const int linear = blockIdx.x;
    const int xc  = linear & 7;            // XCD class
    const int idx = linear >> 3;
    const int bh  = xc * 8 + (idx & 7);    // 8 bh per XCD class
    const int qblk = 31 - (idx >> 3);      // heavy q-tiles dispatch first
    const int q0 = qblk * 64;
    const int b = bh >> 4, h = bh & 15;
    const size_t base = (size_t)bh * 2048 * 64;

    unsigned short* Kw = (unsigned short*)(smem + wave * 16384);  // 8KB
    unsigned short* Vw = Kw + 4096;                               // 8KB

    const int row8 = lane >> 3;                 // 0..7
    const int chx8 = ((lane & 7) ^ row8) * 8;   // XOR-swizzled source chunk

#define STAGE_K(J0) do { _Pragma("unroll") for (int op = 0; op < 8; ++op) \
    async_ld16(kb + base + (size_t)((J0) + op*8 + row8)*64 + chx8, \
               (char*)Kw + op*1024); } while (0)
#define STAGE_V(J0) do { _Pragma("unroll") for (int op = 0; op < 8; ++op) \
    async_ld16(vtb + base + (size_t)(op*8 + row8)*2048 + (J0) + chx8, \
               (char*)Vw + op*1024); } while (0)

    // Q fragments (B-operand), hoisted to registers: qf[ks][nq]
    short8 qf[2][4];
    #pragma unroll
    for (int ks = 0; ks < 2; ++ks)
        #pragma unroll
        for (int nq = 0; nq < 4; ++nq)
            qf[ks][nq] = *(const short8*)(qb + base
                + (size_t)(q0 + nq*16 + l15)*64 + ks*32 + lq*8);

    f32x4 o[4][4] = {};          // [nq][nd]: q=nq*16+lq*4+r, d=nd*16+l15
    float lacc[4] = {0.f, 0.f, 0.f, 0.f};

    const int jfirst = wave * 64;
    const int nt = (qblk >= wave) ? ((qblk - wave) >> 2) + 1 : 0;

    if (nt > 0) { STAGE_K(jfirst); STAGE_V(jfirst); }

    for (int i = 0; i < nt; ++i) {
        const int j0 = jfirst + i * 256;
        const bool more = (i + 1 < nt);

        // K(t) ready (V(t)'s 8 loads remain outstanding)
        asm volatile("s_waitcnt vmcnt(8)" ::: "memory");

        // ---- QK^T (swapped): s[ni][nq], k=ni*16+lq*4+r, q=nq*16+l15 ----
        short8 kf0[4], kf1[4];
        #pragma unroll
        for (int ni = 0; ni < 4; ++ni) {
            const unsigned short* kr = Kw + (ni*16 + l15) * 64;
            kf0[ni] = *(const short8*)(kr + (((0*4 + lq) ^ (l15 & 7)) << 3));
            kf1[ni] = *(const short8*)(kr + (((1*4 + lq) ^ (l15 & 7)) << 3));
        }
        f32x4 s[4][4] = {};
        __builtin_amdgcn_s_setprio(1);
        #pragma unroll
        for (int ni = 0; ni < 4; ++ni)
            #pragma unroll
            for (int nq = 0; nq < 4; ++nq) {
                s[ni][nq] = MFMA_BF16(kf0[ni], qf[0][nq], s[ni][nq], 0, 0, 0);
                s[ni][nq] = MFMA_BF16(kf1[ni], qf[1][nq], s[ni][nq], 0, 0, 0);
            }
        __builtin_amdgcn_s_setprio(0);
        // K reads retired -> safe to overwrite K buffer with next tile
        asm volatile("s_waitcnt lgkmcnt(0)" ::: "memory");
        if (more) STAGE_K(j0 + 256);

        // ---- causal mask (diagonal tile only) ----
        if (j0 == q0) {
            #pragma unroll
            for (int ni = 0; ni < 4; ++ni)
                #pragma unroll
                for (int nq = 0; nq < 4; ++nq)
                    #pragma unroll
                    for (int r = 0; r < 4; ++r)
                        if (ni*16 + lq*4 + r > nq*16 + l15)
                            s[ni][nq][r] = -1e30f;
        }

        // ---- p = exp2(s); pack PV A-fragments in-lane; accumulate l ----
        short8 pf[2][4];
        #pragma unroll
        for (int c = 0; c < 2; ++c)
            #pragma unroll
            for (int nq = 0; nq < 4; ++nq) {
                float p0 = __builtin_amdgcn_exp2f(s[2*c  ][nq][0]);
                float p1 = __builtin_amdgcn_exp2f(s[2*c  ][nq][1]);
                float p2 = __builtin_amdgcn_exp2f(s[2*c  ][nq][2]);
                float p3 = __builtin_amdgcn_exp2f(s[2*c  ][nq][3]);
                float p4 = __builtin_amdgcn_exp2f(s[2*c+1][nq][0]);
                float p5 = __builtin_amdgcn_exp2f(s[2*c+1][nq][1]);
                float p6 = __builtin_amdgcn_exp2f(s[2*c+1][nq][2]);
                float p7 = __builtin_amdgcn_exp2f(s[2*c+1][nq][3]);
                lacc[nq] += ((p0 + p1) + (p2 + p3)) + ((p4 + p5) + (p6 + p7));
                uint4 pu;
                pu.x = pk_bf16(p0, p1); pu.y = pk_bf16(p2, p3);
                pu.z = pk_bf16(p4, p5); pu.w = pk_bf16(p6, p7);
                pf[c][nq] = __builtin_bit_cast(short8, pu);
            }

        // V(t) ready (K(t+1) outstanding if issued)
        if (more) asm volatile("s_waitcnt vmcnt(8)" ::: "memory");
        else      asm volatile("s_waitcnt vmcnt(0)" ::: "memory");

        // ---- PV: o[nq][nd] += pf[c][nq] x vf[c][nd] ----
        #pragma unroll
        for (int c = 0; c < 2; ++c) {
            short8 vf[4];
            #pragma unroll
            for (int nd = 0; nd < 4; ++nd)
                vf[nd] = *(const short8*)(Vw + (nd*16 + l15) * 64
                    + (((c*4 + lq) ^ (l15 & 7)) << 3));
            __builtin_amdgcn_s_setprio(1);
            #pragma unroll
            for (int nq = 0; nq < 4; ++nq)
                #pragma unroll
                for (int nd = 0; nd < 4; ++nd)
                    o[nq][nd] = MFMA_BF16(pf[c][nq], vf[nd], o[nq][nd], 0, 0, 0);
            __builtin_amdgcn_s_setprio(0);
        }
        // V reads retired -> safe to overwrite V buffer
        asm volatile("s_waitcnt lgkmcnt(0)" ::: "memory");
        if (more) STAGE_V(j0 + 256);
    }
#undef STAGE_K
#undef STAGE_V

    // ---- cross-wave combine ----
    // 1) per-wave l partials (reduce over lq groups), store 64 f32 per region
    #pragma unroll
    for (int nq = 0; nq < 4; ++nq) {
        float t = lacc[nq];
        t += __shfl_xor(t, 16);
        t += __shfl_xor(t, 32);
        if (lq == 0) ((float*)Kw)[nq*16 + l15] = t;
    }
    __syncthreads();
    // 2) each thread computes linv for its 16 q rows (qg = wave)
    const int qg = wave, d = lane;
    f32x4 linv4[4];
    #pragma unroll
    for (int j = 0; j < 4; ++j) {
        f32x4 lsum = {};
        #pragma unroll
        for (int w2 = 0; w2 < 4; ++w2)
            lsum += *(const f32x4*)((const float*)(smem + w2*16384) + qg*16 + j*4);
        #pragma unroll
        for (int r = 0; r < 4; ++r)
            linv4[j][r] = __builtin_amdgcn_rcpf(lsum[r]);
    }
    __syncthreads();
    // 3) write O partials (rotated cols: col = (q + 4*(d&15)) & 63)
    #pragma unroll
    for (int nq = 0; nq < 4; ++nq)
        #pragma unroll
        for (int nd = 0; nd < 4; ++nd) {
            const int row = nd*16 + l15;
            const int col = (nq*16 + lq*4 + 4*l15) & 63;
            *(f32x4*)((float*)Kw + row*64 + col) = o[nq][nd];
        }
    __syncthreads();
    // 4) sum 4 partials, normalize, store bf16 (coalesced 128B per wave-store)
    #pragma unroll
    for (int j = 0; j < 4; ++j) {
        const int colb = (qg*16 + j*4 + 4*(d & 15)) & 63;
        f32x4 acc = {};
        #pragma unroll
        for (int w2 = 0; w2 < 4; ++w2)
            acc += *(const f32x4*)((const float*)(smem + w2*16384) + d*64 + colb);
        #pragma unroll
        for (int r = 0; r < 4; ++r) {
            const int q = qg*16 + j*4 + r;
            ab[(size_t)(b*2048 + q0 + q)*1024 + h*64 + d] = f2bf(acc[r] * linv4[j][r]);
        }
    }
}

extern "C" void kernel_launch(void* const* d_in, const int* in_sizes, int n_in,
                              void* d_out, int out_size, void* d_ws, size_t ws_size,
                              hipStream_t stream) {
    const float* x      = (const float*)d_in[0];   // [B,T,C]
    const float* w_qkv  = (const float*)d_in[1];   // [C,3C]
    const float* b_qkv  = (const float*)d_in[2];   // [3C]
    const float* w_proj = (const float*)d_in[3];   // [C,C]
    const float* b_proj = (const float*)d_in[4];   // [C]
    float* out = (float*)d_out;                    // [B,T,C] fp32

    unsigned short* xb     = (unsigned short*)d_ws;          // 8192*1024
    unsigned short* wqkvT  = xb + 8388608;                   // 3072*1024
    unsigned short* wprojT = wqkvT + 3145728;                // 1024*1024
    unsigned short* qbuf   = wprojT + 1048576;               // [B,H,T,D]
    unsigned short* kbuf   = qbuf + 8388608;                 // [B,H,T,D]
    unsigned short* vtbuf  = kbuf + 8388608;                 // [B,H,D,T']
    unsigned short* abuf   = vtbuf + 8388608;                // [B*T][C]
    // total: 46,137,344 bf16 elems = 92 MiB

    prep_all<<<12288, 256, 0, stream>>>(x, w_qkv, w_proj, xb, wqkvT, wprojT);
    gemm_qkv<<<1536, 256, 0, stream>>>(xb, wqkvT, b_qkv, qbuf, kbuf, vtbuf);
    attn_mfma<<<2048, 256, 65536, stream>>>(qbuf, kbuf, vtbuf, abuf);
    gemm_proj<<<512, 256, 0, stream>>>(abuf, wprojT, b_proj, out);
}

// Round 13
// 237.438 us; speedup vs baseline: 1.1387x; 1.0230x over previous
//
#include <hip/hip_runtime.h>

#define B_ 4
#define T_ 2048
#define C_ 1024
#define H_ 16
#define D_ 64

typedef __attribute__((ext_vector_type(8))) short short8;
typedef __attribute__((ext_vector_type(4))) float f32x4;

// float -> bf16 round-to-nearest-even (fallback)
__device__ inline unsigned short f2bf(float f) {
    union { float f; unsigned u; } v; v.f = f;
    unsigned r = v.u + 0x7fffu + ((v.u >> 16) & 1u);
    return (unsigned short)(r >> 16);
}

// pack two fp32 -> packed bf16x2 (v_cvt_pk_bf16_f32 on gfx950)
__device__ inline unsigned int pk_bf16(float a, float b) {
#if __has_builtin(__builtin_amdgcn_cvt_pk_bf16_f32)
    typedef __attribute__((ext_vector_type(2))) __bf16 bf16x2;
    bf16x2 v = __builtin_amdgcn_cvt_pk_bf16_f32(a, b);
    return __builtin_bit_cast(unsigned int, v);
#else
    return (unsigned)f2bf(a) | ((unsigned)f2bf(b) << 16);
#endif
}

// async 16B global -> LDS (wave-uniform LDS base + lane*16)
__device__ inline void async_ld16(const void* g, void* lds) {
    __builtin_amdgcn_global_load_lds(
        (const __attribute__((address_space(1))) unsigned int*)g,
        (__attribute__((address_space(3))) unsigned int*)lds, 16, 0, 0);
}

#define MFMA_BF16 __builtin_amdgcn_mfma_f32_16x16x32_bf16

// ---------------------------------------------------------------------------
// Merged prep: bid<8192 -> x fp32->bf16 convert; else 32x32 transpose-convert
// of w_qkv (128 col-tiles) / w_proj (32 col-tiles) into [n][k] bf16.
// (unchanged; passing)
// ---------------------------------------------------------------------------
__global__ __launch_bounds__(256) void prep_all(
    const float* __restrict__ x, const float* __restrict__ w_qkv,
    const float* __restrict__ w_proj,
    unsigned short* __restrict__ xb, unsigned short* __restrict__ wqkvT,
    unsigned short* __restrict__ wprojT)
{
    const int bid = blockIdx.x;
    if (bid < 8192) {
        int i = (bid * 256 + threadIdx.x) * 4;
        float4 v = *(const float4*)(x + i);
        uint2 o;
        o.x = pk_bf16(v.x, v.y);
        o.y = pk_bf16(v.z, v.w);
        *(uint2*)(xb + i) = o;
        return;
    }
    __shared__ float tile[32][33];
    const int tt = bid - 8192;          // 0..4095
    int bx = tt & 127;                  // col tile
    const int by = tt >> 7;             // row tile (0..31)
    const float* src; unsigned short* dst; int Cc;
    if (bx < 96) { src = w_qkv;  dst = wqkvT;  Cc = 3072; }
    else         { src = w_proj; dst = wprojT; Cc = 1024; bx -= 96; }
    const int tx = threadIdx.x & 31, ty = threadIdx.x >> 5;
    #pragma unroll
    for (int r = 0; r < 32; r += 8)
        tile[ty + r][tx] = src[(size_t)(by*32 + ty + r) * Cc + bx*32 + tx];
    __syncthreads();
    #pragma unroll
    for (int r = 0; r < 32; r += 8)
        dst[(size_t)(bx*32 + ty + r) * 1024 + by*32 + tx] = f2bf(tile[tx][ty + r]);
}

// ---------------------------------------------------------------------------
// QKV GEMM (round-6 version, the proven family optimum): 128x128 tile,
// 256 threads, BK=64, 128B-row XOR-swizzled LDS (0 conflicts measured),
// double-buffered 64KB, prefetch-before-compute, __syncthreads-only sync.
// Family ladder (measured): R9 16 MFMA/pair = 97.8us; R5 serial = 73.3us;
// R6 dbuf = 71.6us; v7 64/pair @1blk/CU = 90us; counted-vmcnt graft =
// 79.8us; 8-phase packagings crashed or spilled.  R6 is the optimum.
// Grid: 1536 = 8 xcd x 8 m_l x 24 n (XCD-affine A-slices).
// ---------------------------------------------------------------------------
__global__ __launch_bounds__(256) void gemm_qkv(
    const unsigned short* __restrict__ A,   // [8192][1024] bf16
    const unsigned short* __restrict__ BT,  // [3072][1024] bf16
    const float* __restrict__ bias,         // [3072] fp32
    unsigned short* __restrict__ qb, unsigned short* __restrict__ kb,
    unsigned short* __restrict__ vtb)
{
    __shared__ unsigned short As[2][128 * 64];   // 2 x 16KB, 128B rows
    __shared__ unsigned short Bs[2][128 * 64];   // 2 x 16KB
    const int tid = threadIdx.x;
    const int wave = tid >> 6, lane = tid & 63;
    const int wm = wave >> 1, wn = wave & 1;
    const int l15 = lane & 15, lq = lane >> 4;
    const int bid = blockIdx.x;
    const int xcd = bid & 7, idx = bid >> 3;         // idx: 0..191
    const int m0 = (xcd * 8 + (idx & 7)) * 128;      // 64 m-tiles
    const int n0 = (idx >> 3) * 128;                 // 24 n-tiles
    const int sel = n0 >> 10;                        // 0=q 1=k 2=v
    const int row8 = lane >> 3;                      // 0..7
    const int chx8 = ((lane & 7) ^ row8) * 8;        // XOR-swizzled src chunk
    const int cxa = l15 & 7;                         // read-side XOR key

    f32x4 acc[4][4] = {};

#define STAGE(buf, K0) do { _Pragma("unroll") \
    for (int c = 0; c < 4; ++c) { \
        const int r = wave*32 + c*8; \
        async_ld16(A  + (size_t)(m0 + r + row8)*1024 + (K0) + chx8, \
                   (char*)&As[buf][0] + r*128); \
        async_ld16(BT + (size_t)(n0 + r + row8)*1024 + (K0) + chx8, \
                   (char*)&Bs[buf][0] + r*128); \
    } } while (0)

    STAGE(0, 0);
    __syncthreads();                       // buf0 ready

    for (int t = 0; t < 16; ++t) {
        const int cur = t & 1;
        if (t < 15) STAGE(cur ^ 1, (t + 1) << 6);   // prefetch under compute
        const unsigned short* Ac = &As[cur][0];
        const unsigned short* Bc = &Bs[cur][0];
        #pragma unroll
        for (int ks = 0; ks < 2; ++ks) {
            short8 af[4], bf[4];
            #pragma unroll
            for (int i = 0; i < 4; ++i) {
                const int ra = wm*64 + i*16 + l15;
                const int rb = wn*64 + i*16 + l15;
                af[i] = *(const short8*)&Ac[ra*64 + (((ks*4 + lq) ^ cxa) << 3)];
                bf[i] = *(const short8*)&Bc[rb*64 + (((ks*4 + lq) ^ cxa) << 3)];
            }
            if (sel < 2) {
                #pragma unroll
                for (int mi = 0; mi < 4; ++mi)
                    #pragma unroll
                    for (int ni = 0; ni < 4; ++ni)
                        acc[mi][ni] = MFMA_BF16(bf[ni], af[mi], acc[mi][ni], 0, 0, 0);
            } else {
                #pragma unroll
                for (int mi = 0; mi < 4; ++mi)
                    #pragma unroll
                    for (int ni = 0; ni < 4; ++ni)
                        acc[mi][ni] = MFMA_BF16(af[mi], bf[ni], acc[mi][ni], 0, 0, 0);
            }
        }
        __syncthreads();   // publishes buf[t+1] (vmcnt drain) + retires reads
    }
#undef STAGE

    if (sel < 2) {
        // lane l15 -> t; reg r -> d. 4 consecutive d per lane -> 8B store.
        const float qs = (sel == 0) ? 0.180336880f : 1.0f;  // 0.125*log2(e) | 1
        unsigned short* dst = (sel == 0) ? qb : kb;
        #pragma unroll
        for (int mi = 0; mi < 4; ++mi) {
            const int t = m0 + wm*64 + mi*16 + l15;
            const int bb = t >> 11, tt = t & 2047;
            #pragma unroll
            for (int ni = 0; ni < 4; ++ni) {
                const int nb = n0 + wn*64 + ni*16 + lq*4;
                const int hh = (nb >> 6) & 15, d0 = nb & 63;
                float4 bv = *(const float4*)(bias + nb);
                float v0 = (acc[mi][ni][0] + bv.x) * qs;
                float v1 = (acc[mi][ni][1] + bv.y) * qs;
                float v2 = (acc[mi][ni][2] + bv.z) * qs;
                float v3 = (acc[mi][ni][3] + bv.w) * qs;
                uint2 pk; pk.x = pk_bf16(v0, v1); pk.y = pk_bf16(v2, v3);
                *(uint2*)(dst + ((size_t)(bb*16 + hh)*2048 + tt)*64 + d0) = pk;
            }
        }
    } else {
        // lane l15 -> d; reg r -> t. 4 consecutive t per lane -> 8B store.
        // column permuted within each 64-tile: t' = c<<5 | lq2<<3 | h<<2 | r
        #pragma unroll
        for (int mi = 0; mi < 4; ++mi) {
            const int t0 = m0 + wm*64 + mi*16 + lq*4;
            const int bb = t0 >> 11, tt = t0 & 2047;
            const int tl = tt & 63;
            const int tp = (tt & ~63) | (tl & 32) | ((tl & 12) << 1) | ((tl & 16) >> 2);
            #pragma unroll
            for (int ni = 0; ni < 4; ++ni) {
                const int n = n0 + wn*64 + ni*16 + l15;
                const int hh = (n >> 6) & 15, d = n & 63;
                const float bs = bias[n];
                uint2 pk;
                pk.x = pk_bf16(acc[mi][ni][0] + bs, acc[mi][ni][1] + bs);
                pk.y = pk_bf16(acc[mi][ni][2] + bs, acc[mi][ni][3] + bs);
                *(uint2*)(vtb + ((size_t)(bb*16 + hh)*64 + d)*2048 + tp) = pk;
            }
        }
    }
}

// ---------------------------------------------------------------------------
// Output projection GEMM (round-6 version): 128x128 tile, BK=64, double-
// buffered 64KB LDS, prefetch-before-compute, __syncthreads-only sync;
// swapped operands -> float4 coalesced stores.  Grid: 512 = 8x8x8.
// ---------------------------------------------------------------------------
__global__ __launch_bounds__(256) void gemm_proj(
    const unsigned short* __restrict__ A,   // [8192][1024] bf16
    const unsigned short* __restrict__ BT,  // [1024][1024] bf16
    const float* __restrict__ bias,         // [1024]
    float* __restrict__ out)
{
    __shared__ unsigned short As[2][128 * 64];
    __shared__ unsigned short Bs[2][128 * 64];
    const int tid = threadIdx.x;
    const int wave = tid >> 6, lane = tid & 63;
    const int wm = wave >> 1, wn = wave & 1;
    const int l15 = lane & 15, lq = lane >> 4;
    const int bid = blockIdx.x;
    const int xcd = bid & 7, idx = bid >> 3;         // idx: 0..63
    const int m0 = (xcd * 8 + (idx & 7)) * 128;      // 64 m-tiles
    const int n0 = (idx >> 3) * 128;                 // 8 n-tiles
    const int row8 = lane >> 3;
    const int chx8 = ((lane & 7) ^ row8) * 8;
    const int cxa = l15 & 7;

    f32x4 acc[4][4] = {};

#define PSTAGE(buf, K0) do { _Pragma("unroll") \
    for (int c = 0; c < 4; ++c) { \
        const int r = wave*32 + c*8; \
        async_ld16(A  + (size_t)(m0 + r + row8)*1024 + (K0) + chx8, \
                   (char*)&As[buf][0] + r*128); \
        async_ld16(BT + (size_t)(n0 + r + row8)*1024 + (K0) + chx8, \
                   (char*)&Bs[buf][0] + r*128); \
    } } while (0)

    PSTAGE(0, 0);
    __syncthreads();

    for (int t = 0; t < 16; ++t) {
        const int cur = t & 1;
        if (t < 15) PSTAGE(cur ^ 1, (t + 1) << 6);
        const unsigned short* Ac = &As[cur][0];
        const unsigned short* Bc = &Bs[cur][0];
        #pragma unroll
        for (int ks = 0; ks < 2; ++ks) {
            short8 af[4], bf[4];
            #pragma unroll
            for (int i = 0; i < 4; ++i) {
                const int ra = wm*64 + i*16 + l15;
                const int rb = wn*64 + i*16 + l15;
                af[i] = *(const short8*)&Ac[ra*64 + (((ks*4 + lq) ^ cxa) << 3)];
                bf[i] = *(const short8*)&Bc[rb*64 + (((ks*4 + lq) ^ cxa) << 3)];
            }
            #pragma unroll
            for (int mi = 0; mi < 4; ++mi)
                #pragma unroll
                for (int ni = 0; ni < 4; ++ni)
                    acc[mi][ni] = MFMA_BF16(bf[ni], af[mi], acc[mi][ni], 0, 0, 0);
        }
        __syncthreads();
    }
#undef PSTAGE

    #pragma unroll
    for (int mi = 0; mi < 4; ++mi) {
        const int m = m0 + wm*64 + mi*16 + l15;
        #pragma unroll
        for (int ni = 0; ni < 4; ++ni) {
            const int nb = n0 + wn*64 + ni*16 + lq*4;
            float4 bv = *(const float4*)(bias + nb);
            float4 o;
            o.x = acc[mi][ni][0] + bv.x;
            o.y = acc[mi][ni][1] + bv.y;
            o.z = acc[mi][ni][2] + bv.z;
            o.w = acc[mi][ni][3] + bv.w;
            *(float4*)(out + (size_t)m * 1024 + nb) = o;
        }
    }
}

// ---------------------------------------------------------------------------
// MFMA flash attention v5 (round-6 version, setprio reverted — R12 measured
// it as ~+7us on attn: with only 2 waves/SIMD the priority boost is zero-sum
// between identical pipelines and the toggling is pure overhead): no-max
// exp2 softmax, 4 waves split k-tiles, private K/V LDS regions, counted-
// vmcnt pipeline, no barriers in main loop, P stays in registers (swapped
// QK^T + pre-permuted V layout).  Cross-wave o/l combine at end.
// ---------------------------------------------------------------------------
__global__ __launch_bounds__(256, 2) void attn_mfma(
    const unsigned short* __restrict__ qb,   // [B,H,T,D]
    const unsigned short* __restrict__ kb,   // [B,H,T,D]
    const unsigned short* __restrict__ vtb,  // [B,H,D,T'] (64-tile permuted)
    unsigned short* __restrict__ ab)         // [B*T][C]
{
    extern __shared__ unsigned char smem[];  // 4 x 16KB wave regions = 64KB
    const int tid  = threadIdx.x;
    const int wave = tid >> 6, lane = tid & 63;
    const int l15  = lane & 15, lq = lane >> 4;
    const int linear = blockIdx.x;
    const int xc  = linear & 7;            // XCD class
    const int idx = linear >> 3;
    const int bh  = xc * 8 + (idx & 7);    // 8 bh per XCD class
    const int qblk = 31 - (idx >> 3);      // heavy q-tiles dispatch first
    const int q0 = qblk * 64;
    const int b = bh >> 4, h = bh & 15;
    const size_t base = (size_t)bh * 2048 * 64;

    unsigned short* Kw = (unsigned short*)(smem + wave * 16384);  // 8KB
    unsigned short* Vw = Kw + 4096;                               // 8KB

    const int row8 = lane >> 3;                 // 0..7
    const int chx8 = ((lane & 7) ^ row8) * 8;   // XOR-swizzled source chunk

#define STAGE_K(J0) do { _Pragma("unroll") for (int op = 0; op < 8; ++op) \
    async_ld16(kb + base + (size_t)((J0) + op*8 + row8)*64 + chx8, \
               (char*)Kw + op*1024); } while (0)
#define STAGE_V(J0) do { _Pragma("unroll") for (int op = 0; op < 8; ++op) \
    async_ld16(vtb + base + (size_t)(op*8 + row8)*2048 + (J0) + chx8, \
               (char*)Vw + op*1024); } while (0)

    // Q fragments (B-operand), hoisted to registers: qf[ks][nq]
    short8 qf[2][4];
    #pragma unroll
    for (int ks = 0; ks < 2; ++ks)
        #pragma unroll
        for (int nq = 0; nq < 4; ++nq)
            qf[ks][nq] = *(const short8*)(qb + base
                + (size_t)(q0 + nq*16 + l15)*64 + ks*32 + lq*8);

    f32x4 o[4][4] = {};          // [nq][nd]: q=nq*16+lq*4+r, d=nd*16+l15
    float lacc[4] = {0.f, 0.f, 0.f, 0.f};

    const int jfirst = wave * 64;
    const int nt = (qblk >= wave) ? ((qblk - wave) >> 2) + 1 : 0;

    if (nt > 0) { STAGE_K(jfirst); STAGE_V(jfirst); }

    for (int i = 0; i < nt; ++i) {
        const int j0 = jfirst + i * 256;
        const bool more = (i + 1 < nt);

        // K(t) ready (V(t)'s 8 loads remain outstanding)
        asm volatile("s_waitcnt vmcnt(8)" ::: "memory");

        // ---- QK^T (swapped): s[ni][nq], k=ni*16+lq*4+r, q=nq*16+l15 ----
        short8 kf0[4], kf1[4];
        #pragma unroll
        for (int ni = 0; ni < 4; ++ni) {
            const unsigned short* kr = Kw + (ni*16 + l15) * 64;
            kf0[ni] = *(const short8*)(kr + (((0*4 + lq) ^ (l15 & 7)) << 3));
            kf1[ni] = *(const short8*)(kr + (((1*4 + lq) ^ (l15 & 7)) << 3));
        }
        f32x4 s[4][4] = {};
        #pragma unroll
        for (int ni = 0; ni < 4; ++ni)
            #pragma unroll
            for (int nq = 0; nq < 4; ++nq) {
                s[ni][nq] = MFMA_BF16(kf0[ni], qf[0][nq], s[ni][nq], 0, 0, 0);
                s[ni][nq] = MFMA_BF16(kf1[ni], qf[1][nq], s[ni][nq], 0, 0, 0);
            }
        // K reads retired -> safe to overwrite K buffer with next tile
        asm volatile("s_waitcnt lgkmcnt(0)" ::: "memory");
        if (more) STAGE_K(j0 + 256);

        // ---- causal mask (diagonal tile only) ----
        if (j0 == q0) {
            #pragma unroll
            for (int ni = 0; ni < 4; ++ni)
                #pragma unroll
                for (int nq = 0; nq < 4; ++nq)
                    #pragma unroll
                    for (int r = 0; r < 4; ++r)
                        if (ni*16 + lq*4 + r > nq*16 + l15)
                            s[ni][nq][r] = -1e30f;
        }

        // ---- p = exp2(s); pack PV A-fragments in-lane; accumulate l ----
        short8 pf[2][4];
        #pragma unroll
        for (int c = 0; c < 2; ++c)
            #pragma unroll
            for (int nq = 0; nq < 4; ++nq) {
                float p0 = __builtin_amdgcn_exp2f(s[2*c  ][nq][0]);
                float p1 = __builtin_amdgcn_exp2f(s[2*c  ][nq][1]);
                float p2 = __builtin_amdgcn_exp2f(s[2*c  ][nq][2]);
                float p3 = __builtin_amdgcn_exp2f(s[2*c  ][nq][3]);
                float p4 = __builtin_amdgcn_exp2f(s[2*c+1][nq][0]);
                float p5 = __builtin_amdgcn_exp2f(s[2*c+1][nq][1]);
                float p6 = __builtin_amdgcn_exp2f(s[2*c+1][nq][2]);
                float p7 = __builtin_amdgcn_exp2f(s[2*c+1][nq][3]);
                lacc[nq] += ((p0 + p1) + (p2 + p3)) + ((p4 + p5) + (p6 + p7));
                uint4 pu;
                pu.x = pk_bf16(p0, p1); pu.y = pk_bf16(p2, p3);
                pu.z = pk_bf16(p4, p5); pu.w = pk_bf16(p6, p7);
                pf[c][nq] = __builtin_bit_cast(short8, pu);
            }

        // V(t) ready (K(t+1) outstanding if issued)
        if (more) asm volatile("s_waitcnt vmcnt(8)" ::: "memory");
        else      asm volatile("s_waitcnt vmcnt(0)" ::: "memory");

        // ---- PV: o[nq][nd] += pf[c][nq] x vf[c][nd] ----
        #pragma unroll
        for (int c = 0; c < 2; ++c) {
            short8 vf[4];
            #pragma unroll
            for (int nd = 0; nd < 4; ++nd)
                vf[nd] = *(const short8*)(Vw + (nd*16 + l15) * 64
                    + (((c*4 + lq) ^ (l15 & 7)) << 3));
            #pragma unroll
            for (int nq = 0; nq < 4; ++nq)
                #pragma unroll
                for (int nd = 0; nd < 4; ++nd)
                    o[nq][nd] = MFMA_BF16(pf[c][nq], vf[nd], o[nq][nd], 0, 0, 0);
        }
        // V reads retired -> safe to overwrite V buffer
        asm volatile("s_waitcnt lgkmcnt(0)" ::: "memory");
        if (more) STAGE_V(j0 + 256);
    }
#undef STAGE_K
#undef STAGE_V

    // ---- cross-wave combine ----
    // 1) per-wave l partials (reduce over lq groups), store 64 f32 per region
    #pragma unroll
    for (int nq = 0; nq < 4; ++nq) {
        float t = lacc[nq];
        t += __shfl_xor(t, 16);
        t += __shfl_xor(t, 32);
        if (lq == 0) ((float*)Kw)[nq*16 + l15] = t;
    }
    __syncthreads();
    // 2) each thread computes linv for its 16 q rows (qg = wave)
    const int qg = wave, d = lane;
    f32x4 linv4[4];
    #pragma unroll
    for (int j = 0; j < 4; ++j) {
        f32x4 lsum = {};
        #pragma unroll
        for (int w2 = 0; w2 < 4; ++w2)
            lsum += *(const f32x4*)((const float*)(smem + w2*16384) + qg*16 + j*4);
        #pragma unroll
        for (int r = 0; r < 4; ++r)
            linv4[j][r] = __builtin_amdgcn_rcpf(lsum[r]);
    }
    __syncthreads();
    // 3) write O partials (rotated cols: col = (q + 4*(d&15)) & 63)
    #pragma unroll
    for (int nq = 0; nq < 4; ++nq)
        #pragma unroll
        for (int nd = 0; nd < 4; ++nd) {
            const int row = nd*16 + l15;
            const int col = (nq*16 + lq*4 + 4*l15) & 63;
            *(f32x4*)((float*)Kw + row*64 + col) = o[nq][nd];
        }
    __syncthreads();
    // 4) sum 4 partials, normalize, store bf16 (coalesced 128B per wave-store)
    #pragma unroll
    for (int j = 0; j < 4; ++j) {
        const int colb = (qg*16 + j*4 + 4*(d & 15)) & 63;
        f32x4 acc = {};
        #pragma unroll
        for (int w2 = 0; w2 < 4; ++w2)
            acc += *(const f32x4*)((const float*)(smem + w2*16384) + d*64 + colb);
        #pragma unroll
        for (int r = 0; r < 4; ++r) {
            const int q = qg*16 + j*4 + r;
            ab[(size_t)(b*2048 + q0 + q)*1024 + h*64 + d] = f2bf(acc[r] * linv4[j][r]);
        }
    }
}

extern "C" void kernel_launch(void* const* d_in, const int* in_sizes, int n_in,
                              void* d_out, int out_size, void* d_ws, size_t ws_size,
                              hipStream_t stream) {
    const float* x      = (const float*)d_in[0];   // [B,T,C]
    const float* w_qkv  = (const float*)d_in[1];   // [C,3C]
    const float* b_qkv  = (const float*)d_in[2];   // [3C]
    const float* w_proj = (const float*)d_in[3];   // [C,C]
    const float* b_proj = (const float*)d_in[4];   // [C]
    float* out = (float*)d_out;                    // [B,T,C] fp32

    unsigned short* xb     = (unsigned short*)d_ws;          // 8192*1024
    unsigned short* wqkvT  = xb + 8388608;                   // 3072*1024
    unsigned short* wprojT = wqkvT + 3145728;                // 1024*1024
    unsigned short* qbuf   = wprojT + 1048576;               // [B,H,T,D]
    unsigned short* kbuf   = qbuf + 8388608;                 // [B,H,T,D]
    unsigned short* vtbuf  = kbuf + 8388608;                 // [B,H,D,T']
    unsigned short* abuf   = vtbuf + 8388608;                // [B*T][C]
    // total: 46,137,344 bf16 elems = 92 MiB

    prep_all<<<12288, 256, 0, stream>>>(x, w_qkv, w_proj, xb, wqkvT, wprojT);
    gemm_qkv<<<1536, 256, 0, stream>>>(xb, wqkvT, b_qkv, qbuf, kbuf, vtbuf);
    attn_mfma<<<2048, 256, 65536, stream>>>(qbuf, kbuf, vtbuf, abuf);
    gemm_proj<<<512, 256, 0, stream>>>(abuf, wprojT, b_proj, out);
}